// Round 5
// baseline (529.183 us; speedup 1.0000x reference)
//
#include <hip/hip_runtime.h>
#include <math.h>

// ---------------------------------------------------------------------------
// VAE ELBO (chromatin VAE). Sizes fixed by the reference.
//
//  * NB_ENC == NB_DEC == 16, identical binning => ONE nibble histogram serves
//    both the encoder input (log1p counts) and the mixture likelihood.
//  * r3/r4 lesson: random global atomics cost ~32B HBM-side RMW *when the
//    working set exceeds the 4 MB per-XCD L2* (r4's 8.2 MB replica thrashed;
//    frag's 2 MB replica was fast). Fix: 4 gene-range passes so each pass's
//    per-XCD atomic slice is 2.05 MB (L2-resident). Per-pass replicas are
//    merged into the final hist and re-zeroed between passes.
//  * hist = 4-bit counters (8 cells/u32): P(count>=16) ~ 1e-16 at lambda=.25.
//    frag = u16 pairs (single pass, 2 MB replica fits L2).
//  * enc reads the merged hist (8 MB), 500 blocks, LDS-combines row-lanes,
//    emits per-chunk partials (no float atomics); bn reduces partials.
//  * All sums -> one f64 accumulator; N_CUTS*log(16) folded at finalize.
// ---------------------------------------------------------------------------

#define G_      1000
#define C_      1024
#define L_      50
#define K_      16
#define NHID_   16
#define CUT_SCALE   12.5f          // N_TOTAL_CUTS / N_CUTS
#define CELL_SCALE  9.765625f      // N_TOTAL_CELLS / N_CELLS

#define GPP_    250                // genes per hist pass
#define SLICEW_ 512000u            // nibble words per pass slice (250*16*128)
#define FWORDS_ 512000u            // u16 frag words per replica (1000*512)
#define NCHUNK_ 500                // encoder partial chunks

__device__ __forceinline__ unsigned int xcc_id() {
    unsigned int x;
    asm volatile("s_getreg_b32 %0, hwreg(HW_REG_XCC_ID, 0, 4)" : "=s"(x));
    return x & 7u;
}

__device__ __forceinline__ float block_sum_256(float v) {
    __shared__ float sm[256];
    int t = threadIdx.x;
    __syncthreads();
    sm[t] = v;
    __syncthreads();
#pragma unroll
    for (int s = 128; s > 0; s >>= 1) {
        if (t < s) sm[t] += sm[t + s];
        __syncthreads();
    }
    return sm[0];
}

// --- 1. cut histogram pass: genes [g_lo,g_hi), per-XCD 2 MB slice ----------
template<bool WG>
__global__ void hist_kernel(const float* __restrict__ coord,
                            const int* __restrict__ cxg,
                            unsigned int* __restrict__ histr, int n,
                            int g_lo, int g_hi) {
    int i = blockIdx.x * 256 + threadIdx.x;
    if (i >= n) return;
    int ix = __builtin_nontemporal_load(&cxg[i]);
    int c = ix / G_;
    int g = ix - c * G_;
    if (g < g_lo || g >= g_hi) return;
    float x = __builtin_nontemporal_load(&coord[i]);
    int b = (int)(x * 16.0f);
    b = b > 15 ? 15 : b;
    unsigned int word = (unsigned int)((g - g_lo) * K_ + b) * (C_ / 8)
                      + ((unsigned)c >> 3);
    unsigned int inc = 1u << ((c & 7) * 4);
    if (WG) {
        unsigned int* H = histr + (size_t)xcc_id() * SLICEW_;
        __hip_atomic_fetch_add(&H[word], inc, __ATOMIC_RELAXED,
                               __HIP_MEMORY_SCOPE_WORKGROUP);
    } else {
        atomicAdd(&histr[word], inc);
    }
}

// --- 1b. merge pass replicas -> merged slice; re-zero replicas -------------
template<int NREP>
__global__ void merge_kernel(unsigned int* __restrict__ histr,
                             unsigned int* __restrict__ merged_slice,
                             int rezero) {
    unsigned int w = blockIdx.x * 256 + threadIdx.x;
    if (w >= SLICEW_) return;
    unsigned int s = 0;
#pragma unroll
    for (int r = 0; r < NREP; ++r) {
        s += histr[(size_t)r * SLICEW_ + w];
        if (rezero) histr[(size_t)r * SLICEW_ + w] = 0;
    }
    merged_slice[w] = s;
}

// --- 2. fragment counts: u16 (g, c) += 1, per-XCD 2 MB replica -------------
template<bool WG>
__global__ void frag_kernel(const int* __restrict__ fix,
                            unsigned int* __restrict__ fragr, int n) {
    int i = blockIdx.x * 256 + threadIdx.x;
    if (i >= n) return;
    int ix = __builtin_nontemporal_load(&fix[i]);
    int c = ix / G_;
    int g = ix - c * G_;
    unsigned int word = ((unsigned int)(g * C_) + (unsigned)c) >> 1;
    unsigned int inc = 1u << ((c & 1) * 16);
    if (WG) {
        unsigned int* F = fragr + (size_t)xcc_id() * FWORDS_;
        __hip_atomic_fetch_add(&F[word], inc, __ATOMIC_RELAXED,
                               __HIP_MEMORY_SCOPE_WORKGROUP);
    } else {
        atomicAdd(&fragr[word], inc);
    }
}

// --- 3. encoder matmul from merged hist ------------------------------------
// 500 blocks x 256 thr; 32 rows/block; word w = t&127 (8 cells), rl = t>>7.
__global__ __launch_bounds__(256)
void enc_kernel(const unsigned int* __restrict__ merged, // [16000][128]
                const float* __restrict__ W1,            // [16000][16]
                float* __restrict__ P) {                 // [500][16][1024]
    int t = threadIdx.x;
    int w = t & 127;
    int rl = t >> 7;
    int row0 = blockIdx.x * 32;
    float acc[NHID_][8];
#pragma unroll
    for (int j = 0; j < NHID_; ++j)
#pragma unroll
        for (int u = 0; u < 8; ++u) acc[j][u] = 0.f;
    for (int it = 0; it < 16; ++it) {
        int row = row0 + it * 2 + rl;
        unsigned int mw = merged[(unsigned)row * 128u + (unsigned)w];
        float xv[8];
#pragma unroll
        for (int u = 0; u < 8; ++u)
            xv[u] = __logf((float)(((mw >> (u * 4)) & 0xfu) + 1u));
        const float* wr = W1 + (size_t)row * NHID_;   // wave-uniform -> s_load
#pragma unroll
        for (int j = 0; j < NHID_; ++j) {
            float wj = wr[j];
#pragma unroll
            for (int u = 0; u < 8; ++u) acc[j][u] = fmaf(xv[u], wj, acc[j][u]);
        }
    }
    __shared__ float sp[NHID_][128][8];   // 64 KB
    if (rl == 1) {
#pragma unroll
        for (int j = 0; j < NHID_; ++j)
#pragma unroll
            for (int u = 0; u < 8; ++u) sp[j][w][u] = acc[j][u];
    }
    __syncthreads();
    if (rl == 0) {
        float* Pp = P + (size_t)blockIdx.x * (NHID_ * C_) + (w * 8);
#pragma unroll
        for (int j = 0; j < NHID_; ++j)
#pragma unroll
            for (int u = 0; u < 8; ++u)
                Pp[j * C_ + u] = acc[j][u] + sp[j][w][u];
    }
}

// --- 4. reduce partials -> hT[j][c]; f64 BN sums ---------------------------
// grid (16 j, 16 cell-tiles) x 64 threads (one wave)
__global__ __launch_bounds__(64)
void bn_kernel(const float* __restrict__ P,
               float* __restrict__ hT,
               double* __restrict__ bnsum) {  // [0..15]=sum, [16..31]=sumsq
    int j = blockIdx.x;
    int c = blockIdx.y * 64 + threadIdx.x;
    float s = 0.f;
#pragma unroll 8
    for (int ch = 0; ch < NCHUNK_; ++ch)
        s += P[((size_t)ch * NHID_ + j) * C_ + c];
    hT[j * C_ + c] = s;
    float s1 = s, s2 = s * s;
#pragma unroll
    for (int o = 32; o > 0; o >>= 1) {
        s1 += __shfl_down(s1, o);
        s2 += __shfl_down(s2, o);
    }
    if (threadIdx.x == 0) {
        atomicAdd(&bnsum[j], (double)s1);
        atomicAdd(&bnsum[NHID_ + j], (double)s2);
    }
}

// --- 5. latent sample + latent KL (BN scale/shift derived inline) ----------
__global__ __launch_bounds__(256)
void latent_kernel(const float* __restrict__ hT,
                   const double* __restrict__ bnsum,
                   const float* __restrict__ gamma,
                   const float* __restrict__ beta,
                   const float* __restrict__ W_loc,   // [16][50]
                   const float* __restrict__ b_loc,
                   const float* __restrict__ W_scale, // [16][50]
                   const float* __restrict__ b_scale,
                   const float* __restrict__ eps,     // [1024][50]
                   float* __restrict__ latT,          // [50][1024]
                   double* __restrict__ acc) {
    int idx = blockIdx.x * 256 + threadIdx.x;
    float kl = 0.f;
    if (idx < C_ * L_) {
        int c = idx / L_;
        int l = idx - c * L_;
        float hb[NHID_];
#pragma unroll
        for (int j = 0; j < NHID_; ++j) {
            float mean = (float)(bnsum[j] * (1.0 / C_));
            float ex2  = (float)(bnsum[NHID_ + j] * (1.0 / C_));
            float var = ex2 - mean * mean;
            float rstd = rsqrtf(var + 1e-5f);
            float sc = gamma[j] * rstd;
            float sh = beta[j] - mean * sc;
            float v = fmaf(hT[j * C_ + c], sc, sh);
            hb[j] = v > 0.f ? v : 0.f;
        }
        float loc = b_loc[l], ls = b_scale[l];
#pragma unroll
        for (int j = 0; j < NHID_; ++j) {
            loc = fmaf(hb[j], W_loc[j * L_ + l], loc);
            ls  = fmaf(hb[j], W_scale[j * L_ + l], ls);
        }
        float qs = 0.1f * __expf(ls);
        float e = eps[idx];
        float lat = fmaf(qs, e, loc);
        latT[(size_t)l * C_ + c] = lat;
        float z = (lat - loc) / qs;
        kl = fmaf(-0.5f * lat, lat, fmaf(0.5f * z, z, __logf(qs)));
    }
    float s = block_sum_256(kl);
    if (threadIdx.x == 0) atomicAdd(acc, -(double)(CELL_SCALE * s));
}

// --- 6. weight KL (logit_weight + rho_weight), N(0,0.1) --------------------
__global__ __launch_bounds__(256)
void wkl_kernel(const float* __restrict__ lw,  // 800000
                const float* __restrict__ rw,  // 50000
                double* __restrict__ acc) {
    const int NTOT = G_ * L_ * K_ + G_ * L_;   // 850000
    float s = 0.f;
    for (int i = blockIdx.x * 256 + threadIdx.x; i < NTOT; i += gridDim.x * 256) {
        float w = (i < G_ * L_ * K_) ? lw[i] : rw[i - G_ * L_ * K_];
        s += fmaf(-50.f * w, w, 1.3836465597893733f);
    }
    s = block_sum_256(s);
    if (threadIdx.x == 0) atomicAdd(acc, -(double)s);
}

// --- 7. fused decoder: mixture + Poisson likelihood per (c,g) --------------
// grid (1000 genes, 4 cell-tiles) x 256 threads
template<int NREP>
__global__ __launch_bounds__(256)
void main_kernel(const float* __restrict__ latT,         // [50][1024]
                 const unsigned int* __restrict__ merged,// [16000][128] nibble
                 const unsigned int* __restrict__ fragr, // u16 replicas
                 const float* __restrict__ lw,           // [1000][50][16]
                 const float* __restrict__ rw,           // [1000][50]
                 const float* __restrict__ baseline,     // [1000][16]
                 const float* __restrict__ rho_bias,     // [1000]
                 const int* __restrict__ libsize,
                 double* __restrict__ acc) {
    int g = blockIdx.x;
    int c = blockIdx.y * 256 + threadIdx.x;
    const float* lwg = lw + (size_t)g * (L_ * K_);   // wave-uniform base
    const float* rwg = rw + (size_t)g * L_;
    float logits[K_];
#pragma unroll
    for (int k = 0; k < K_; ++k) logits[k] = baseline[g * K_ + k];
    float rho = 0.f;
    for (int l = 0; l < L_; ++l) {
        float lv = latT[(size_t)l * C_ + c];         // coalesced
        rho = fmaf(lv, rwg[l], rho);
#pragma unroll
        for (int k = 0; k < K_; ++k)
            logits[k] = fmaf(lv, lwg[l * K_ + k], logits[k]);
    }
    float m = logits[0];
#pragma unroll
    for (int k = 1; k < K_; ++k) m = fmaxf(m, logits[k]);
    float se = 0.f;
#pragma unroll
    for (int k = 0; k < K_; ++k) se += __expf(logits[k] - m);
    float lse = m + __logf(se);
    float mix = 0.f;
    int sh4 = (c & 7) * 4;
#pragma unroll
    for (int k = 0; k < K_; ++k) {
        unsigned int cw = merged[(unsigned)(g * K_ + k) * (C_ / 8) + ((unsigned)c >> 3)];
        float cnt = (float)((cw >> sh4) & 0xfu);
        mix = fmaf(cnt, logits[k] - lse, mix);
    }
    unsigned int fw = ((unsigned)(g * C_) + (unsigned)c) >> 1;
    unsigned int fsh = (c & 1) * 16;
    unsigned int fcnt = 0;
#pragma unroll
    for (int r = 0; r < NREP; ++r)
        fcnt += (fragr[(size_t)r * FWORDS_ + fw] >> fsh) & 0xffffu;
    float fc = (float)fcnt;
    float fe = rho_bias[g] * __expf(rho) * (float)libsize[c];
    float lf = fmaf(fc, __logf(fe), -fe) - lgammaf(fc + 1.0f);
    float v = -(CUT_SCALE * mix + CELL_SCALE * lf);
    float s = block_sum_256(v);
    if (threadIdx.x == 0) atomicAdd(acc, (double)s);
}

// --- 8. finalize -----------------------------------------------------------
__global__ void final_kernel(const double* __restrict__ acc, float* __restrict__ out) {
    // -12.5 * 4e6 * log(16)
    out[0] = (float)(acc[0] - 138629436.11198905);
}

extern "C" void kernel_launch(void* const* d_in, const int* in_sizes, int n_in,
                              void* d_out, int out_size, void* d_ws, size_t ws_size,
                              hipStream_t stream) {
    const float* cut_coord = (const float*)d_in[0];
    const float* eps       = (const float*)d_in[1];
    const float* enc_W1    = (const float*)d_in[2];
    // d_in[3] = enc_b1 : cancels through BatchNorm, unused
    const float* bn_gamma  = (const float*)d_in[4];
    const float* bn_beta   = (const float*)d_in[5];
    const float* W_loc     = (const float*)d_in[6];
    const float* b_loc     = (const float*)d_in[7];
    const float* W_scale   = (const float*)d_in[8];
    const float* b_scale   = (const float*)d_in[9];
    const float* logit_w   = (const float*)d_in[10];
    const float* rho_w     = (const float*)d_in[11];
    const float* baseline  = (const float*)d_in[12];
    const float* rho_bias  = (const float*)d_in[13];
    const int* cut_cxg     = (const int*)d_in[14];
    const int* frag_ix     = (const int*)d_in[16];
    const int* libsize     = (const int*)d_in[19];

    int n_cuts  = in_sizes[0];
    int n_frags = in_sizes[16];

    const size_t SLICE_B = (size_t)SLICEW_ * 4;     // 2,048,000
    const size_t FRAG_B  = (size_t)FWORDS_ * 4;     // 2,048,000
    auto need = [&](size_t nrep) {
        return nrep * (SLICE_B + FRAG_B) + 264ull
             + 8192000ull + 32768000ull + 65536ull + 204800ull;
    };
    int nrep = (ws_size >= need(8)) ? 8 : 1;

    char* ws = (char*)d_ws;
    size_t histr_off  = 0;
    size_t fragr_off  = histr_off + (size_t)nrep * SLICE_B;
    size_t acc_off    = fragr_off + (size_t)nrep * FRAG_B;
    size_t bnsum_off  = acc_off + 8;
    size_t zero_end   = bnsum_off + 256;
    size_t merged_off = zero_end;
    size_t p_off      = merged_off + 8192000ull;
    size_t ht_off     = p_off + 32768000ull;
    size_t latt_off   = ht_off + 65536ull;

    unsigned int* histr  = (unsigned int*)(ws + histr_off);
    unsigned int* fragr  = (unsigned int*)(ws + fragr_off);
    double*       acc    = (double*)(ws + acc_off);
    double*       bnsum  = (double*)(ws + bnsum_off);
    unsigned int* merged = (unsigned int*)(ws + merged_off);
    float*        P      = (float*)(ws + p_off);
    float*        hT     = (float*)(ws + ht_off);
    float*        latT   = (float*)(ws + latt_off);
    float*        out    = (float*)d_out;

    hipMemsetAsync(ws, 0, zero_end, stream);

    int hist_grid = (n_cuts + 255) / 256;
    int frag_grid = (n_frags + 255) / 256;
    int merge_grid = (SLICEW_ + 255) / 256;

    if (nrep == 8) {
        frag_kernel<true><<<frag_grid, 256, 0, stream>>>(frag_ix, fragr, n_frags);
        for (int p = 0; p < 4; ++p) {
            hist_kernel<true><<<hist_grid, 256, 0, stream>>>(
                cut_coord, cut_cxg, histr, n_cuts, p * GPP_, (p + 1) * GPP_);
            merge_kernel<8><<<merge_grid, 256, 0, stream>>>(
                histr, merged + (size_t)p * SLICEW_, p < 3);
        }
    } else {
        frag_kernel<false><<<frag_grid, 256, 0, stream>>>(frag_ix, fragr, n_frags);
        for (int p = 0; p < 4; ++p) {
            hist_kernel<false><<<hist_grid, 256, 0, stream>>>(
                cut_coord, cut_cxg, histr, n_cuts, p * GPP_, (p + 1) * GPP_);
            merge_kernel<1><<<merge_grid, 256, 0, stream>>>(
                histr, merged + (size_t)p * SLICEW_, p < 3);
        }
    }
    enc_kernel<<<NCHUNK_, 256, 0, stream>>>(merged, enc_W1, P);
    bn_kernel<<<dim3(16, 16), 64, 0, stream>>>(P, hT, bnsum);
    latent_kernel<<<(C_ * L_ + 255) / 256, 256, 0, stream>>>(
        hT, bnsum, bn_gamma, bn_beta, W_loc, b_loc, W_scale, b_scale,
        eps, latT, acc);
    wkl_kernel<<<512, 256, 0, stream>>>(logit_w, rho_w, acc);
    if (nrep == 8)
        main_kernel<8><<<dim3(G_, 4), 256, 0, stream>>>(
            latT, merged, fragr, logit_w, rho_w, baseline, rho_bias, libsize, acc);
    else
        main_kernel<1><<<dim3(G_, 4), 256, 0, stream>>>(
            latT, merged, fragr, logit_w, rho_w, baseline, rho_bias, libsize, acc);
    final_kernel<<<1, 1, 0, stream>>>(acc, out);
}

// Round 6
// 347.228 us; speedup vs baseline: 1.5240x; 1.5240x over previous
//
#include <hip/hip_runtime.h>
#include <math.h>

// ---------------------------------------------------------------------------
// VAE ELBO (chromatin VAE). Sizes fixed by the reference.
//
//  * NB_ENC == NB_DEC == 16, identical binning => ONE nibble histogram serves
//    both the encoder input (log1p counts) and the mixture likelihood.
//  * r3-r5 lesson (3x replicated): global atomics on gfx950 execute
//    memory-side regardless of scope/footprint: ~32B transaction each,
//    ~26 G/s device-wide (WRITE_SIZE == 32B x n_atomics in every config).
//    Fix: NO per-record global atomics. Two-phase LDS counting sort:
//      phase1: workgroup-local radix partition into 256 buckets
//              (cellgroup64 x binchunk1024); 256 reserve-atomics per wg only.
//      phase2: workgroup per bucket; LDS nibble histogram (1024 bins x 64
//              cells = 32 KB); writeback owns whole 32B sectors (cellgroup
//              = 64 cells = 1 sector/bin) -> plain stores, no false sharing.
//  * hist = 4-bit counters (P(count>=16) ~ 1e-16 at lambda=.25, r4/r5-proven);
//    frag = u8 counters (lambda=1.95, max ~12).
//  * enc reads merged hist (8 MB), W1 wave-uniform s_loads, per-chunk
//    partials (no float atomics); bn reduces partials -> f64 BN sums.
//  * All sums -> one f64 accumulator; N_CUTS*log(16) folded at finalize.
// ---------------------------------------------------------------------------

#define G_      1000
#define C_      1024
#define L_      50
#define K_      16
#define NHID_   16
#define CUT_SCALE   12.5f          // N_TOTAL_CUTS / N_CUTS
#define CELL_SCALE  9.765625f      // N_TOTAL_CELLS / N_CELLS

#define NCHUNK_   500              // encoder partial chunks
#define RCAP_CUT  18432            // bucket capacity, cuts  (mean 16000, +19s)
#define RCAP_FRAG 9216             // bucket capacity, frags (mean 8000, +13s)

// ws layout (bytes)
#define CTL_OFF    0ull            // gcount_cut[256] | gcount_frag[256] | acc | bnsum[32]
#define ZERO_BYTES 2312ull
#define ENTC_OFF   4096ull         // u16 [256][18432]
#define ENTF_OFF   9441280ull      // u16 [256][9216]
#define MERGED_OFF 14159872ull     // u32 [16000][128] nibble hist
#define FRAGU8_OFF 22351872ull     // u8  [1000][1024]
#define P_OFF      23375872ull     // f32 [500][16][1024]
#define HT_OFF     56143872ull     // f32 [16][1024]
#define LATT_OFF   56209408ull     // f32 [50][1024]
#define WS_NEED    56414208ull

__device__ __forceinline__ float block_sum_256(float v) {
    __shared__ float sm[256];
    int t = threadIdx.x;
    __syncthreads();
    sm[t] = v;
    __syncthreads();
#pragma unroll
    for (int s = 128; s > 0; s >>= 1) {
        if (t < s) sm[t] += sm[t + s];
        __syncthreads();
    }
    return sm[0];
}

// --- 1. radix partition into 256 buckets (MODE 0 = cuts, 1 = frags) --------
// 4096 records/wg: LDS count -> prefix -> global reserve (256 atomics/wg)
// -> LDS bucket-sorted stage -> coalesced u16 writeout.
template<int MODE>
__global__ __launch_bounds__(256)
void part_kernel(const int* __restrict__ idx,
                 const float* __restrict__ coord,   // unused for MODE 1
                 unsigned int* __restrict__ gcount,
                 unsigned short* __restrict__ ent,
                 int n, int rcap) {
    __shared__ unsigned int cnt[256], excl[256], cur[256], gbase_s[256];
    __shared__ unsigned short stage[4096];
    __shared__ unsigned char bkof[4096];
    int t = threadIdx.x;
    int i0 = blockIdx.x * 4096;
    unsigned char mybk[16];
    unsigned short myent[16];
    bool myval[16];
    cnt[t] = 0;
    __syncthreads();
#pragma unroll
    for (int k = 0; k < 16; ++k) {
        int i = i0 + k * 256 + t;
        bool v = (i < n);
        unsigned int bk = 0; unsigned short e = 0;
        if (v) {
            int ix = idx[i];
            int c = ix / G_;
            int g = ix - c * G_;
            if (MODE == 0) {
                float x = coord[i];
                int b = (int)(x * 16.0f); b = b > 15 ? 15 : b;
                int bin = g * K_ + b;
                bk = ((unsigned)(c >> 6) << 4) | ((unsigned)bin >> 10);
                e = (unsigned short)(((c & 63) << 10) | (bin & 1023));
            } else {
                bk = ((unsigned)(c >> 6) << 4) | ((unsigned)g >> 6);
                e = (unsigned short)(((c & 63) << 6) | (g & 63));
            }
            atomicAdd(&cnt[bk], 1u);   // LDS atomic
        }
        mybk[k] = (unsigned char)bk; myent[k] = e; myval[k] = v;
    }
    __syncthreads();
    // Hillis-Steele inclusive prefix over 256 buckets
    excl[t] = cnt[t];
    __syncthreads();
    for (int o = 1; o < 256; o <<= 1) {
        unsigned int v = (t >= o) ? excl[t - o] : 0u;
        __syncthreads();
        excl[t] += v;
        __syncthreads();
    }
    unsigned int my_excl = excl[t] - cnt[t];
    gbase_s[t] = cnt[t] ? atomicAdd(&gcount[t], cnt[t]) : 0u;  // global reserve
    cur[t] = my_excl;
    __syncthreads();
    excl[t] = my_excl;
    __syncthreads();
#pragma unroll
    for (int k = 0; k < 16; ++k) {
        if (myval[k]) {
            unsigned int p = atomicAdd(&cur[mybk[k]], 1u);   // LDS atomic
            stage[p] = myent[k];
            bkof[p] = mybk[k];
        }
    }
    __syncthreads();
    unsigned int total = excl[255] + cnt[255];
    for (unsigned int p = t; p < total; p += 256) {
        unsigned int bk = bkof[p];
        unsigned int dst = gbase_s[bk] + (p - excl[bk]);
        if (dst < (unsigned)rcap)
            ent[(size_t)bk * rcap + dst] = stage[p];
    }
}

// --- 2a. per-bucket cut histogram: LDS nibbles -> sector-exclusive store ---
__global__ __launch_bounds__(256)
void hist2_kernel(const unsigned int* __restrict__ gcount,
                  const unsigned short* __restrict__ ent,
                  unsigned int* __restrict__ merged) {  // [16000][128] words
    __shared__ unsigned int h[8192];   // 1024 bins x 8 words (64 cells nibble)
    int t = threadIdx.x;
    int bk = blockIdx.x;
    int cg = bk >> 4, bc = bk & 15;
    for (int i = t; i < 8192; i += 256) h[i] = 0;
    __syncthreads();
    unsigned int count = gcount[bk];
    if (count > RCAP_CUT) count = RCAP_CUT;
    const unsigned short* e = ent + (size_t)bk * RCAP_CUT;
    for (unsigned int p = t; p < count; p += 256) {
        unsigned int v = e[p];
        unsigned int bin_lo = v & 1023u;
        unsigned int c_lo = v >> 10;
        atomicAdd(&h[bin_lo * 8 + (c_lo >> 3)], 1u << ((c_lo & 7) * 4));
    }
    __syncthreads();
    for (int i = t; i < 8192; i += 256) {
        int bin = bc * 1024 + (i >> 3);
        if (bin < 16000)
            merged[(unsigned)bin * 128u + (unsigned)cg * 8u + (i & 7)] = h[i];
    }
}

// --- 2b. per-bucket frag counts: LDS u16 -> u8 sector-exclusive store ------
__global__ __launch_bounds__(256)
void frag2_kernel(const unsigned int* __restrict__ gcount,
                  const unsigned short* __restrict__ ent,
                  unsigned int* __restrict__ fragw) {   // u8[1000][1024] as u32
    __shared__ unsigned int f[2048];   // 64 g x 32 words (2 u16 cells/word)
    int t = threadIdx.x;
    int bk = blockIdx.x;
    int cg = bk >> 4, gc = bk & 15;
    for (int i = t; i < 2048; i += 256) f[i] = 0;
    __syncthreads();
    unsigned int count = gcount[bk];
    if (count > RCAP_FRAG) count = RCAP_FRAG;
    const unsigned short* e = ent + (size_t)bk * RCAP_FRAG;
    for (unsigned int p = t; p < count; p += 256) {
        unsigned int v = e[p];
        unsigned int g_lo = v & 63u;
        unsigned int c_lo = v >> 6;
        atomicAdd(&f[g_lo * 32 + (c_lo >> 1)], 1u << ((c_lo & 1) * 16));
    }
    __syncthreads();
    for (int i = t; i < 1024; i += 256) {  // 64 g x 16 output words
        int g_lo = i >> 4, wb = i & 15;
        unsigned int lo = f[g_lo * 32 + wb * 2];
        unsigned int hi = f[g_lo * 32 + wb * 2 + 1];
        unsigned int out = (lo & 0xffu) | (((lo >> 16) & 0xffu) << 8)
                         | ((hi & 0xffu) << 16) | (((hi >> 16) & 0xffu) << 24);
        int g = gc * 64 + g_lo;
        if (g < G_)
            fragw[(unsigned)g * 256u + (unsigned)cg * 16u + wb] = out;
    }
}

// --- 3. encoder matmul from merged hist ------------------------------------
// 500 blocks x 256 thr; 32 rows/block; word w = t&127 (8 cells), rl = t>>7.
__global__ __launch_bounds__(256)
void enc_kernel(const unsigned int* __restrict__ merged, // [16000][128]
                const float* __restrict__ W1,            // [16000][16]
                float* __restrict__ P) {                 // [500][16][1024]
    int t = threadIdx.x;
    int w = t & 127;
    int rl = t >> 7;
    int row0 = blockIdx.x * 32;
    float acc[NHID_][8];
#pragma unroll
    for (int j = 0; j < NHID_; ++j)
#pragma unroll
        for (int u = 0; u < 8; ++u) acc[j][u] = 0.f;
    for (int it = 0; it < 16; ++it) {
        int row = row0 + it * 2 + rl;
        unsigned int mw = merged[(unsigned)row * 128u + (unsigned)w];
        float xv[8];
#pragma unroll
        for (int u = 0; u < 8; ++u)
            xv[u] = __logf((float)(((mw >> (u * 4)) & 0xfu) + 1u));
        const float* wr = W1 + (size_t)row * NHID_;   // wave-uniform -> s_load
#pragma unroll
        for (int j = 0; j < NHID_; ++j) {
            float wj = wr[j];
#pragma unroll
            for (int u = 0; u < 8; ++u) acc[j][u] = fmaf(xv[u], wj, acc[j][u]);
        }
    }
    __shared__ float sp[NHID_][128][8];   // 64 KB
    if (rl == 1) {
#pragma unroll
        for (int j = 0; j < NHID_; ++j)
#pragma unroll
            for (int u = 0; u < 8; ++u) sp[j][w][u] = acc[j][u];
    }
    __syncthreads();
    if (rl == 0) {
        float* Pp = P + (size_t)blockIdx.x * (NHID_ * C_) + (w * 8);
#pragma unroll
        for (int j = 0; j < NHID_; ++j)
#pragma unroll
            for (int u = 0; u < 8; ++u)
                Pp[j * C_ + u] = acc[j][u] + sp[j][w][u];
    }
}

// --- 4. reduce partials -> hT[j][c]; f64 BN sums ---------------------------
__global__ __launch_bounds__(64)
void bn_kernel(const float* __restrict__ P,
               float* __restrict__ hT,
               double* __restrict__ bnsum) {  // [0..15]=sum, [16..31]=sumsq
    int j = blockIdx.x;
    int c = blockIdx.y * 64 + threadIdx.x;
    float s = 0.f;
#pragma unroll 8
    for (int ch = 0; ch < NCHUNK_; ++ch)
        s += P[((size_t)ch * NHID_ + j) * C_ + c];
    hT[j * C_ + c] = s;
    float s1 = s, s2 = s * s;
#pragma unroll
    for (int o = 32; o > 0; o >>= 1) {
        s1 += __shfl_down(s1, o);
        s2 += __shfl_down(s2, o);
    }
    if (threadIdx.x == 0) {
        atomicAdd(&bnsum[j], (double)s1);
        atomicAdd(&bnsum[NHID_ + j], (double)s2);
    }
}

// --- 5. latent sample + latent KL (BN scale/shift derived inline) ----------
__global__ __launch_bounds__(256)
void latent_kernel(const float* __restrict__ hT,
                   const double* __restrict__ bnsum,
                   const float* __restrict__ gamma,
                   const float* __restrict__ beta,
                   const float* __restrict__ W_loc,   // [16][50]
                   const float* __restrict__ b_loc,
                   const float* __restrict__ W_scale, // [16][50]
                   const float* __restrict__ b_scale,
                   const float* __restrict__ eps,     // [1024][50]
                   float* __restrict__ latT,          // [50][1024]
                   double* __restrict__ acc) {
    int idx = blockIdx.x * 256 + threadIdx.x;
    float kl = 0.f;
    if (idx < C_ * L_) {
        int c = idx / L_;
        int l = idx - c * L_;
        float hb[NHID_];
#pragma unroll
        for (int j = 0; j < NHID_; ++j) {
            float mean = (float)(bnsum[j] * (1.0 / C_));
            float ex2  = (float)(bnsum[NHID_ + j] * (1.0 / C_));
            float var = ex2 - mean * mean;
            float rstd = rsqrtf(var + 1e-5f);
            float sc = gamma[j] * rstd;
            float sh = beta[j] - mean * sc;
            float v = fmaf(hT[j * C_ + c], sc, sh);
            hb[j] = v > 0.f ? v : 0.f;
        }
        float loc = b_loc[l], ls = b_scale[l];
#pragma unroll
        for (int j = 0; j < NHID_; ++j) {
            loc = fmaf(hb[j], W_loc[j * L_ + l], loc);
            ls  = fmaf(hb[j], W_scale[j * L_ + l], ls);
        }
        float qs = 0.1f * __expf(ls);
        float e = eps[idx];
        float lat = fmaf(qs, e, loc);
        latT[(size_t)l * C_ + c] = lat;
        float z = (lat - loc) / qs;
        kl = fmaf(-0.5f * lat, lat, fmaf(0.5f * z, z, __logf(qs)));
    }
    float s = block_sum_256(kl);
    if (threadIdx.x == 0) atomicAdd(acc, -(double)(CELL_SCALE * s));
}

// --- 6. weight KL (logit_weight + rho_weight), N(0,0.1) --------------------
__global__ __launch_bounds__(256)
void wkl_kernel(const float* __restrict__ lw,  // 800000
                const float* __restrict__ rw,  // 50000
                double* __restrict__ acc) {
    const int NTOT = G_ * L_ * K_ + G_ * L_;   // 850000
    float s = 0.f;
    for (int i = blockIdx.x * 256 + threadIdx.x; i < NTOT; i += gridDim.x * 256) {
        float w = (i < G_ * L_ * K_) ? lw[i] : rw[i - G_ * L_ * K_];
        s += fmaf(-50.f * w, w, 1.3836465597893733f);
    }
    s = block_sum_256(s);
    if (threadIdx.x == 0) atomicAdd(acc, -(double)s);
}

// --- 7. fused decoder: mixture + Poisson likelihood per (c,g) --------------
__global__ __launch_bounds__(256)
void main_kernel(const float* __restrict__ latT,         // [50][1024]
                 const unsigned int* __restrict__ merged,// [16000][128] nibble
                 const unsigned char* __restrict__ fragb,// [1000][1024] u8
                 const float* __restrict__ lw,           // [1000][50][16]
                 const float* __restrict__ rw,           // [1000][50]
                 const float* __restrict__ baseline,     // [1000][16]
                 const float* __restrict__ rho_bias,     // [1000]
                 const int* __restrict__ libsize,
                 double* __restrict__ acc) {
    int g = blockIdx.x;
    int c = blockIdx.y * 256 + threadIdx.x;
    const float* lwg = lw + (size_t)g * (L_ * K_);   // wave-uniform base
    const float* rwg = rw + (size_t)g * L_;
    float logits[K_];
#pragma unroll
    for (int k = 0; k < K_; ++k) logits[k] = baseline[g * K_ + k];
    float rho = 0.f;
    for (int l = 0; l < L_; ++l) {
        float lv = latT[(size_t)l * C_ + c];         // coalesced
        rho = fmaf(lv, rwg[l], rho);
#pragma unroll
        for (int k = 0; k < K_; ++k)
            logits[k] = fmaf(lv, lwg[l * K_ + k], logits[k]);
    }
    float m = logits[0];
#pragma unroll
    for (int k = 1; k < K_; ++k) m = fmaxf(m, logits[k]);
    float se = 0.f;
#pragma unroll
    for (int k = 0; k < K_; ++k) se += __expf(logits[k] - m);
    float lse = m + __logf(se);
    float mix = 0.f;
    int sh4 = (c & 7) * 4;
#pragma unroll
    for (int k = 0; k < K_; ++k) {
        unsigned int cw = merged[(unsigned)(g * K_ + k) * 128u + ((unsigned)c >> 3)];
        float cnt = (float)((cw >> sh4) & 0xfu);
        mix = fmaf(cnt, logits[k] - lse, mix);
    }
    float fc = (float)fragb[(size_t)g * C_ + c];
    float fe = rho_bias[g] * __expf(rho) * (float)libsize[c];
    float lf = fmaf(fc, __logf(fe), -fe) - lgammaf(fc + 1.0f);
    float v = -(CUT_SCALE * mix + CELL_SCALE * lf);
    float s = block_sum_256(v);
    if (threadIdx.x == 0) atomicAdd(acc, (double)s);
}

// --- 8. finalize -----------------------------------------------------------
__global__ void final_kernel(const double* __restrict__ acc, float* __restrict__ out) {
    // -12.5 * 4e6 * log(16)
    out[0] = (float)(acc[0] - 138629436.11198905);
}

extern "C" void kernel_launch(void* const* d_in, const int* in_sizes, int n_in,
                              void* d_out, int out_size, void* d_ws, size_t ws_size,
                              hipStream_t stream) {
    const float* cut_coord = (const float*)d_in[0];
    const float* eps       = (const float*)d_in[1];
    const float* enc_W1    = (const float*)d_in[2];
    // d_in[3] = enc_b1 : cancels through BatchNorm, unused
    const float* bn_gamma  = (const float*)d_in[4];
    const float* bn_beta   = (const float*)d_in[5];
    const float* W_loc     = (const float*)d_in[6];
    const float* b_loc     = (const float*)d_in[7];
    const float* W_scale   = (const float*)d_in[8];
    const float* b_scale   = (const float*)d_in[9];
    const float* logit_w   = (const float*)d_in[10];
    const float* rho_w     = (const float*)d_in[11];
    const float* baseline  = (const float*)d_in[12];
    const float* rho_bias  = (const float*)d_in[13];
    const int* cut_cxg     = (const int*)d_in[14];
    const int* frag_ix     = (const int*)d_in[16];
    const int* libsize     = (const int*)d_in[19];

    int n_cuts  = in_sizes[0];
    int n_frags = in_sizes[16];

    char* ws = (char*)d_ws;
    unsigned int*  gcnt_c = (unsigned int*)(ws + CTL_OFF);
    unsigned int*  gcnt_f = (unsigned int*)(ws + CTL_OFF + 1024);
    double*        acc    = (double*)(ws + CTL_OFF + 2048);
    double*        bnsum  = (double*)(ws + CTL_OFF + 2056);
    unsigned short* entc  = (unsigned short*)(ws + ENTC_OFF);
    unsigned short* entf  = (unsigned short*)(ws + ENTF_OFF);
    unsigned int*  merged = (unsigned int*)(ws + MERGED_OFF);
    unsigned int*  fragw  = (unsigned int*)(ws + FRAGU8_OFF);
    float*         P      = (float*)(ws + P_OFF);
    float*         hT     = (float*)(ws + HT_OFF);
    float*         latT   = (float*)(ws + LATT_OFF);
    float*         out    = (float*)d_out;

    hipMemsetAsync(ws, 0, ZERO_BYTES, stream);

    part_kernel<0><<<(n_cuts + 4095) / 4096, 256, 0, stream>>>(
        cut_cxg, cut_coord, gcnt_c, entc, n_cuts, RCAP_CUT);
    part_kernel<1><<<(n_frags + 4095) / 4096, 256, 0, stream>>>(
        frag_ix, (const float*)nullptr, gcnt_f, entf, n_frags, RCAP_FRAG);
    hist2_kernel<<<256, 256, 0, stream>>>(gcnt_c, entc, merged);
    frag2_kernel<<<256, 256, 0, stream>>>(gcnt_f, entf, fragw);
    enc_kernel<<<NCHUNK_, 256, 0, stream>>>(merged, enc_W1, P);
    bn_kernel<<<dim3(16, 16), 64, 0, stream>>>(P, hT, bnsum);
    latent_kernel<<<(C_ * L_ + 255) / 256, 256, 0, stream>>>(
        hT, bnsum, bn_gamma, bn_beta, W_loc, b_loc, W_scale, b_scale,
        eps, latT, acc);
    wkl_kernel<<<512, 256, 0, stream>>>(logit_w, rho_w, acc);
    main_kernel<<<dim3(G_, 4), 256, 0, stream>>>(
        latT, merged, (const unsigned char*)fragw, logit_w, rho_w,
        baseline, rho_bias, libsize, acc);
    final_kernel<<<1, 1, 0, stream>>>(acc, out);
}